// Round 8
// baseline (112.101 us; speedup 1.0000x reference)
//
#include <hip/hip_runtime.h>
#include <math.h>

#define NCLS 9
#define DIM 768
#define NPIX 65536   // 4 * 128 * 128
#define NSPLIT 8     // dim-groups of 96

// ---- workspace layout (bytes), no memset needed ----
#define OFF_LAB     ((size_t)0)        // uchar[65536]          = 65536
#define OFF_HIST    ((size_t)65536)    // int[256*9]            = 9216   -> 74752
#define OFF_SUMS    ((size_t)74752)    // float[9*768]          = 27648  -> 102400
#define OFF_SUMSQ   ((size_t)102400)   // float[16] (zeroed by k0)
#define OFF_LOSS    ((size_t)102464)   // float[4]  (zeroed by k0)
#define OFF_DONE    ((size_t)102480)   // uint[4]   (zeroed by k0, k5 ticket)
#define OFF_PROTO   ((size_t)102528)   // float[768*12]         = 36864  -> 139392
#define OFF_LOGITS  ((size_t)139392)   // float[9*65536]        = 2359296 -> 2498688
#define OFF_PART    ((size_t)2498688)  // float[8*9*65536]      = 18874368 -> 21373056
// total ~21.4 MB (ws is ~805 MB per the harness poison-fill size)

__device__ __forceinline__ float waveReduceSum(float v) {
#pragma unroll
  for (int off = 32; off > 0; off >>= 1) v += __shfl_down(v, off, 64);
  return v;
}

// K0: downsample labels -> uchar lab[n]; per-block histogram -> hist[block][9];
// block 0 zero-inits sumsq/lossacc/done for downstream kernels.
__global__ void k0_lab(const int* __restrict__ label, unsigned char* __restrict__ lab,
                       int* __restrict__ hist, float* __restrict__ sumsq,
                       float* __restrict__ lossacc, unsigned int* __restrict__ done) {
  __shared__ int h[NCLS];
  int tid = threadIdx.x;
  if (tid < NCLS) h[tid] = 0;
  __syncthreads();
  int n = blockIdx.x * 256 + tid;
  int b = n >> 14, r = (n >> 7) & 127, cc = n & 127;
  int c = label[b * 262144 + r * 2048 + cc * 4];
  lab[n] = (unsigned char)c;
  atomicAdd(&h[c], 1);
  if (blockIdx.x == 0) {
    if (tid < 16) sumsq[tid] = 0.f;
    else if (tid == 16) lossacc[0] = 0.f;
    else if (tid == 17) done[0] = 0u;
  }
  __syncthreads();
  if (tid < NCLS) hist[blockIdx.x * NCLS + tid] = h[tid];
}

// K1: per-class segment sums. One block per feature dim d. Pure streaming — NO
// fences/tickets (R2: agent-scope fence per block = 5x slowdown).
__global__ void k1_segsum(const float4* __restrict__ feat4, const uchar4* __restrict__ lab4,
                          float* __restrict__ sums) {
  int d = blockIdx.x;
  int tid = threadIdx.x;
  float acc[NCLS];
#pragma unroll
  for (int k = 0; k < NCLS; ++k) acc[k] = 0.f;
  for (int b = 0; b < 4; ++b) {
    const float4* fp = feat4 + (size_t)(b * DIM + d) * 4096;
    const uchar4* lp = lab4 + b * 4096;
#pragma unroll 4
    for (int i = 0; i < 16; ++i) {
      int p = tid + i * 256;
      float4 f = fp[p];
      uchar4 l = lp[p];
      int lx = l.x, ly = l.y, lz = l.z, lw = l.w;
#pragma unroll
      for (int k = 0; k < NCLS; ++k) {
        acc[k] += (lx == k) ? f.x : 0.f;
        acc[k] += (ly == k) ? f.y : 0.f;
        acc[k] += (lz == k) ? f.z : 0.f;
        acc[k] += (lw == k) ? f.w : 0.f;
      }
    }
  }
  __shared__ float red[4][NCLS];
#pragma unroll
  for (int k = 0; k < NCLS; ++k) acc[k] = waveReduceSum(acc[k]);
  int lane = tid & 63, w = tid >> 6;
  if (lane == 0) {
#pragma unroll
    for (int k = 0; k < NCLS; ++k) red[w][k] = acc[k];
  }
  __syncthreads();
  if (tid < NCLS)
    sums[tid * DIM + d] = red[0][tid] + red[1][tid] + red[2][tid] + red[3][tid];
}

// K2: counts from hist; protos = l2norm(0.99*mean + 0.01*proto) -> protoT[768][12]
// in global memory. Single block, 768 threads. Launch cost ~0 (R4 vs R5).
__global__ void k2_proto(const float* __restrict__ sums, const int* __restrict__ hist,
                         const float* __restrict__ proto, float* __restrict__ protoT) {
  __shared__ float red[12][NCLS];
  __shared__ float inv[NCLS];
  __shared__ float cpart[16][NCLS];
  __shared__ float cnt[NCLS];
  int tid = threadIdx.x;  // == d
  if (tid < 144) {
    int c = tid % NCLS, g = tid / NCLS;  // g in 0..15
    int s = 0;
#pragma unroll
    for (int j = 0; j < 16; ++j) s += hist[(g * 16 + j) * NCLS + c];
    cpart[g][c] = (float)s;
  }
  __syncthreads();
  if (tid < NCLS) {
    float s = 0.f;
#pragma unroll
    for (int g = 0; g < 16; ++g) s += cpart[g][tid];
    cnt[tid] = s;
  }
  __syncthreads();
  float v[NCLS];
#pragma unroll
  for (int c = 0; c < NCLS; ++c)
    v[c] = 0.99f * (sums[c * DIM + tid] / cnt[c]) + 0.01f * proto[c * DIM + tid];
  int lane = tid & 63, w = tid >> 6;
#pragma unroll
  for (int c = 0; c < NCLS; ++c) {
    float q = waveReduceSum(v[c] * v[c]);
    if (lane == 0) red[w][c] = q;
  }
  __syncthreads();
  if (tid < NCLS) {
    float t = 0.f;
#pragma unroll
    for (int w2 = 0; w2 < 12; ++w2) t += red[w2][tid];
    inv[tid] = 1.f / fmaxf(sqrtf(t), 1e-12f);
  }
  __syncthreads();
#pragma unroll
  for (int c = 0; c < NCLS; ++c) protoT[tid * 12 + c] = v[c] * inv[c];
}

// K3: split-K logits, DIM-MAJOR contiguous reads. Block = (dim-group g of 96
// dims, px-tile of 1024). Reads 96 rows x 4KB CONTIGUOUS chunks (vs the old
// px-major 1KB slivers at 64KB stride — the inferred ~55us scattered-read
// bottleneck; k1 proves contiguous dim-major sustains ~6TB/s). Each wave's
// partials are final for its pixels: no combine tree, no post-loop barrier,
// plain coalesced write to part[g][9][NPIX].
__global__ void __launch_bounds__(512) k3_splitk(const float* __restrict__ feat,
                                                 const float* __restrict__ protoT,
                                                 float* __restrict__ part) {
  __shared__ float pl[96 * 12];  // 4.6 KB proto slice for this dim-group
  int tid = threadIdx.x;
  int g = blockIdx.x >> 6;   // dim-group 0..7
  int t = blockIdx.x & 63;   // px-tile 0..63 (1024 px each)
  // coalesced proto-slice copy
  if (tid < 288) ((float4*)pl)[tid] = ((const float4*)protoT)[g * 288 + tid];
  __syncthreads();

  int b = t >> 4, pb = (t & 15) * 1024;  // batch, within-batch px offset
  const float* fr = feat + ((size_t)(b * DIM + g * 96)) * 16384 + pb + tid;
  const float* pp = pl;
  float a[NCLS][2];
#pragma unroll
  for (int c = 0; c < NCLS; ++c) { a[c][0] = 0.f; a[c][1] = 0.f; }

#pragma unroll 4
  for (int dd = 0; dd < 96; ++dd) {
    float f0 = fr[0], f1 = fr[512];
    float4 q0 = *(const float4*)pp;
    float4 q1 = *(const float4*)(pp + 4);
    float q8 = pp[8];
    float pcs[NCLS] = {q0.x, q0.y, q0.z, q0.w, q1.x, q1.y, q1.z, q1.w, q8};
#pragma unroll
    for (int c = 0; c < NCLS; ++c) {
      a[c][0] += pcs[c] * f0;
      a[c][1] += pcs[c] * f1;
    }
    fr += 16384;
    pp += 12;
  }

  // final partials for these pixels: plain coalesced global writes
  float* op = part + ((size_t)g * NCLS) * NPIX + t * 1024 + tid;
#pragma unroll
  for (int c = 0; c < NCLS; ++c) {
    op[(size_t)c * NPIX] = a[c][0];
    op[(size_t)c * NPIX + 512] = a[c][1];
  }
}

// K4: combine 8 split-K partials -> logits + per-class sum-of-squares.
__global__ void k4_combine(const float4* __restrict__ part4, float4* __restrict__ logits4,
                           float* __restrict__ sumsq) {
  int t = blockIdx.x * 256 + threadIdx.x;  // float4 index over NPIX/4 = 16384
  int tid = threadIdx.x;
  float ssq[NCLS];
#pragma unroll
  for (int c = 0; c < NCLS; ++c) {
    float4 v = part4[(size_t)(0 * NCLS + c) * 16384 + t];
#pragma unroll
    for (int s = 1; s < NSPLIT; ++s) {
      float4 wv = part4[(size_t)(s * NCLS + c) * 16384 + t];
      v.x += wv.x; v.y += wv.y; v.z += wv.z; v.w += wv.w;
    }
    logits4[(size_t)c * 16384 + t] = v;
    ssq[c] = v.x * v.x + v.y * v.y + v.z * v.z + v.w * v.w;
  }
  __shared__ float red[4][NCLS];
#pragma unroll
  for (int c = 0; c < NCLS; ++c) ssq[c] = waveReduceSum(ssq[c]);
  int lane = tid & 63, w = tid >> 6;
  if (lane == 0) {
#pragma unroll
    for (int c = 0; c < NCLS; ++c) red[w][c] = ssq[c];
  }
  __syncthreads();
  if (tid < NCLS)
    atomicAdd(&sumsq[tid], red[0][tid] + red[1][tid] + red[2][tid] + red[3][tid]);
}

// K5: per-pixel loss + fused finalize via done-ticket.
__global__ void k5_loss(const float4* __restrict__ logits4, const uchar4* __restrict__ lab4,
                        const float* __restrict__ sumsq, float* __restrict__ lossacc,
                        unsigned int* __restrict__ done, float* __restrict__ out) {
  int t = blockIdx.x * 256 + threadIdx.x;  // float4 index over 16384
  int tid = threadIdx.x;
  float scale[NCLS];
#pragma unroll
  for (int c = 0; c < NCLS; ++c) scale[c] = 10.f / fmaxf(sqrtf(sumsq[c]), 1e-12f);
  float arr[NCLS][4];
#pragma unroll
  for (int c = 0; c < NCLS; ++c) {
    float4 v = logits4[(size_t)c * 16384 + t];
    arr[c][0] = v.x; arr[c][1] = v.y; arr[c][2] = v.z; arr[c][3] = v.w;
  }
  uchar4 lb = lab4[t];
  int lv[4] = {lb.x, lb.y, lb.z, lb.w};
  float lsum = 0.f;
#pragma unroll
  for (int j = 0; j < 4; ++j) {
    int l = lv[j];
    int lc = (l == 7) ? 6 : l;
    float sumE = 0.f, picked = 0.f;
#pragma unroll
    for (int c = 0; c < NCLS; ++c) {
      float pf = (c == 2) ? ((lc == 2) ? 1.f : 0.f) : arr[c][j] * scale[c];
      sumE += __expf(pf);
      picked += (c == lc) ? pf : 0.f;
    }
    lsum += __logf(sumE) - picked;
  }
  lsum = waveReduceSum(lsum);
  __shared__ float red[4];
  int lane = tid & 63, w = tid >> 6;
  if (lane == 0) red[w] = lsum;
  __syncthreads();
  if (tid == 0) {
    atomicAdd(lossacc, red[0] + red[1] + red[2] + red[3]);
    __threadfence();
    unsigned int ticket = atomicAdd(done, 1u);
    if (ticket == gridDim.x - 1) {
      __threadfence();
      float total = __hip_atomic_load(lossacc, __ATOMIC_ACQUIRE, __HIP_MEMORY_SCOPE_AGENT);
      out[0] = total * (1.f / (float)NPIX);
    }
  }
}

extern "C" void kernel_launch(void* const* d_in, const int* in_sizes, int n_in,
                              void* d_out, int out_size, void* d_ws, size_t ws_size,
                              hipStream_t stream) {
  // inputs: 0=cls_score (unused), 1=label, 2=gt_lucas (unused), 3=features, 4=prototypes
  const int* label = (const int*)d_in[1];
  const float* feat = (const float*)d_in[3];
  const float* proto = (const float*)d_in[4];
  char* ws = (char*)d_ws;
  unsigned char* lab = (unsigned char*)(ws + OFF_LAB);
  int* hist = (int*)(ws + OFF_HIST);
  float* sums = (float*)(ws + OFF_SUMS);
  float* sumsq = (float*)(ws + OFF_SUMSQ);
  float* lossacc = (float*)(ws + OFF_LOSS);
  unsigned int* done = (unsigned int*)(ws + OFF_DONE);
  float* protoT = (float*)(ws + OFF_PROTO);
  float* logits = (float*)(ws + OFF_LOGITS);
  float* part = (float*)(ws + OFF_PART);

  k0_lab<<<NPIX / 256, 256, 0, stream>>>(label, lab, hist, sumsq, lossacc, done);
  k1_segsum<<<DIM, 256, 0, stream>>>((const float4*)feat, (const uchar4*)lab, sums);
  k2_proto<<<1, 768, 0, stream>>>(sums, hist, proto, protoT);
  k3_splitk<<<NSPLIT * 64, 512, 0, stream>>>(feat, protoT, part);
  k4_combine<<<64, 256, 0, stream>>>((const float4*)part, (float4*)logits, sumsq);
  k5_loss<<<64, 256, 0, stream>>>((const float4*)logits, (const uchar4*)lab, sumsq, lossacc,
                                  done, (float*)d_out);
}